// Round 6
// baseline (203.551 us; speedup 1.0000x reference)
//
#include <hip/hip_runtime.h>

typedef __bf16 bf16x8 __attribute__((ext_vector_type(8)));
typedef float f32x4 __attribute__((ext_vector_type(4)));

__device__ __forceinline__ unsigned short f2bf(float f) {
    unsigned int u = __builtin_bit_cast(unsigned int, f);
    u += 0x7fff + ((u >> 16) & 1);   // round-to-nearest-even (finite inputs)
    return (unsigned short)(u >> 16);
}

// ---------------------------------------------------------------------------
// Stage one 128x64 A-tile + 128x64 B-tile into LDS via global_load_lds.
// Linear LDS dest, source pre-swizzled chunk c^(row&7); read applies same XOR
// (both-sides-or-neither, rule #21). lds: [0..8191]=A, [8192..16383]=B.
// ---------------------------------------------------------------------------
__device__ __forceinline__ void stage_tile(
    const unsigned short* __restrict__ Ap, int lda,
    const unsigned short* __restrict__ Bp, int ldb,
    unsigned short* lds, int k0, int tid)
{
#pragma unroll
    for (int it = 0; it < 4; ++it) {
        int li = it * 256 + tid;          // 0..1023: row = li>>3, chunk = li&7
        int row = li >> 3;
        int sc = ((li & 7) ^ (row & 7)) * 8;
        __builtin_amdgcn_global_load_lds(
            (const __attribute__((address_space(1))) void*)(Ap + (long)row * lda + k0 + sc),
            (__attribute__((address_space(3))) void*)&lds[li * 8], 16, 0, 0);
        __builtin_amdgcn_global_load_lds(
            (const __attribute__((address_space(1))) void*)(Bp + (long)row * ldb + k0 + sc),
            (__attribute__((address_space(3))) void*)&lds[8192 + li * 8], 16, 0, 0);
    }
}

// ---------------------------------------------------------------------------
// Compute one 64-deep K-step from a staged tile pair (swizzled read).
// acc[m][n]: MFMA D row <- A-tile row (wm+m*16+...), D col <- B-tile row.
// ---------------------------------------------------------------------------
__device__ __forceinline__ void compute_tile(
    const unsigned short* lds, int lane, int wm, int wn, f32x4 (&acc)[4][4])
{
#pragma unroll
    for (int kk = 0; kk < 2; ++kk) {
        const int cl = kk * 4 + (lane >> 4);
        bf16x8 af[4], bfr[4];
#pragma unroll
        for (int m = 0; m < 4; ++m) {
            int row = wm + m * 16 + (lane & 15);
            af[m] = *(const bf16x8*)&lds[row * 64 + ((cl ^ (row & 7)) * 8)];
        }
#pragma unroll
        for (int n = 0; n < 4; ++n) {
            int row = wn + n * 16 + (lane & 15);
            bfr[n] = *(const bf16x8*)&lds[8192 + row * 64 + ((cl ^ (row & 7)) * 8)];
        }
#pragma unroll
        for (int m = 0; m < 4; ++m)
#pragma unroll
            for (int n = 0; n < 4; ++n)
                acc[m][n] = __builtin_amdgcn_mfma_f32_16x16x32_bf16(af[m], bfr[n], acc[m][n], 0, 0, 0);
    }
}

// ---------------------------------------------------------------------------
// Build Wcat[g][q][512] = [W_gx | W_gh] rows (bf16) and Woc bf16.
// ---------------------------------------------------------------------------
__global__ __launch_bounds__(256)
void cvt_weights(const float* __restrict__ fx, const float* __restrict__ ix,
                 const float* __restrict__ ox, const float* __restrict__ gx,
                 const float* __restrict__ fh, const float* __restrict__ ih,
                 const float* __restrict__ oh, const float* __restrict__ gh,
                 const float* __restrict__ oc,
                 unsigned short* __restrict__ Wcat, unsigned short* __restrict__ Wocb)
{
    int idx = blockIdx.x * 256 + threadIdx.x;
    if (idx < 524288) {
        int g = idx >> 17;
        int rem = idx & 131071;
        int q = rem >> 9;
        int j = rem & 511;
        const float* xs = (g == 0) ? fx : (g == 1) ? ix : (g == 2) ? ox : gx;
        const float* hs = (g == 0) ? fh : (g == 1) ? ih : (g == 2) ? oh : gh;
        float v = (j < 256) ? xs[q * 256 + j] : hs[q * 256 + (j - 256)];
        Wcat[idx] = f2bf(v);
    } else if (idx < 589824) {
        int k = idx - 524288;
        Wocb[k] = f2bf(oc[k]);
    }
}

// ---------------------------------------------------------------------------
// Stage 1 (right-multiply): S[b][i][q] = sum_j A[b][i][j] * W[q][j], fp32 A
// read natural row-major; epilogue stores S TRANSPOSED (bf16):
//   MODE 0 (gates): A=M_hf (X/H), W=Wcat[g] half hf ->
//                   Tout[g][b][q][hf*256+i], ldc=512. grid (4,128,8).
//   MODE 1 (c):     A=out_c, W=Wocb -> Tout[b][q][i], ldc=256. grid (4,128,1).
// ---------------------------------------------------------------------------
template <int MODE>
__global__ __launch_bounds__(256)
void gemm_stage1(const float* __restrict__ Xf, const float* __restrict__ Hf,
                 const unsigned short* __restrict__ Wb,
                 unsigned short* __restrict__ Tout)
{
    __shared__ alignas(16) unsigned short lds[17408];  // 32KB staging | 128x136 ldsT

    const int tid = threadIdx.x;
    const int lane = tid & 63;
    const int w = tid >> 6;

    int d = blockIdx.x + 4 * blockIdx.y + 512 * blockIdx.z;
    int swz = (MODE == 0) ? ((d & 7) * 512 + (d >> 3))   // 4096 blocks, bijective
                          : ((d & 7) * 64 + (d >> 3));   // 512 blocks, bijective
    const int x = swz & 3;
    const int b = (swz >> 2) & 127;
    const int gz = (MODE == 0) ? (swz >> 9) : 0;
    const int g = gz >> 1, hf = gz & 1;
    const int ti = (x & 1) * 128;      // A rows (i)
    const int tq = (x >> 1) * 128;     // B rows (q)
    const int wm = (w >> 1) * 64;
    const int wn = (w & 1) * 64;
    const int ldb = (MODE == 0) ? 512 : 256;

    const float* Ap = ((MODE == 0) ? (hf ? Hf : Xf) : Xf) + (long)b * 65536 + (long)ti * 256;
    const unsigned short* Bp = (MODE == 0)
        ? Wb + (long)g * 131072 + (long)tq * 512 + hf * 256
        : Wb + (long)tq * 256;

    f32x4 acc[4][4];
#pragma unroll
    for (int m = 0; m < 4; ++m)
#pragma unroll
        for (int n = 0; n < 4; ++n)
            acc[m][n] = (f32x4){0.f, 0.f, 0.f, 0.f};

    float4 pre[4][2];
#pragma unroll
    for (int it = 0; it < 4; ++it) {
        int li = it * 256 + tid;
        int row = li >> 3;
        int ck = li & 7;
        const float* ga = Ap + (long)row * 256 + ck * 8;
        pre[it][0] = *(const float4*)ga;
        pre[it][1] = *(const float4*)(ga + 4);
    }

    for (int t = 0; t < 4; ++t) {
        if (t > 0) __syncthreads();            // prev compute done; lds reusable
#pragma unroll
        for (int it = 0; it < 4; ++it) {       // B-tile via global_load_lds
            int li = it * 256 + tid;
            int row = li >> 3;
            int sc = ((li & 7) ^ (row & 7)) * 8;
            __builtin_amdgcn_global_load_lds(
                (const __attribute__((address_space(1))) void*)(Bp + (long)row * ldb + t * 64 + sc),
                (__attribute__((address_space(3))) void*)&lds[8192 + li * 8], 16, 0, 0);
        }
#pragma unroll
        for (int it = 0; it < 4; ++it) {       // A-tile: cvt fp32->bf16, swizzled write
            int li = it * 256 + tid;
            int row = li >> 3;
            int ck = li & 7;
            const float* pf = (const float*)&pre[it][0];
            uint4 uv;
            uv.x = (unsigned)f2bf(pf[0]) | ((unsigned)f2bf(pf[1]) << 16);
            uv.y = (unsigned)f2bf(pf[2]) | ((unsigned)f2bf(pf[3]) << 16);
            uv.z = (unsigned)f2bf(pf[4]) | ((unsigned)f2bf(pf[5]) << 16);
            uv.w = (unsigned)f2bf(pf[6]) | ((unsigned)f2bf(pf[7]) << 16);
            *(uint4*)&lds[row * 64 + ((ck ^ (row & 7)) * 8)] = uv;
        }
        __syncthreads();                       // drains vmcnt (B) + lgkm (A)
        if (t < 3) {                           // next A fp32 loads under compute
#pragma unroll
            for (int it = 0; it < 4; ++it) {
                int li = it * 256 + tid;
                int row = li >> 3;
                int ck = li & 7;
                const float* ga = Ap + (long)row * 256 + (t + 1) * 64 + ck * 8;
                pre[it][0] = *(const float4*)ga;
                pre[it][1] = *(const float4*)(ga + 4);
            }
        }
        compute_tile(lds, lane, wm, wn, acc);  // acc[i_local][q_local]
    }

    // epilogue: transpose via LDS -> store S_T rows (q-major, i contiguous)
    __syncthreads();
    unsigned short (*ldsT)[136] = (unsigned short(*)[136])lds;
    const int r0 = (lane >> 4) * 4;
    const int c0 = lane & 15;
#pragma unroll
    for (int m = 0; m < 4; ++m)
#pragma unroll
        for (int n = 0; n < 4; ++n)
#pragma unroll
            for (int r = 0; r < 4; ++r) {
                int row = wm + m * 16 + r0 + r;   // local i
                int col = wn + n * 16 + c0;       // local q
                ldsT[col][row] = f2bf(acc[m][n][r]);
            }
    __syncthreads();
    unsigned short* Cb;
    int ldc;
    if (MODE == 0) { Cb = Tout + (long)g * 16777216 + (long)b * 131072 + hf * 256; ldc = 512; }
    else           { Cb = Tout + (long)b * 65536; ldc = 256; }
#pragma unroll
    for (int it = 0; it < 8; ++it) {
        int idx = it * 256 + tid;      // 0..2047
        int qq = idx >> 4;             // local q 0..127
        int ch = idx & 15;             // 16 chunks of 8 el
        uint4 v = *(const uint4*)&ldsT[qq][ch * 8];
        *(uint4*)&Cb[(long)(tq + qq) * ldc + ti + ch * 8] = v;
    }
}

// ---------------------------------------------------------------------------
// Stage 2 (left-multiply), fused gates:
//   out[b][o][q] = sum_{i'} Wcat[g][o][i'] * S_T[g][b][q][i']   (K=512)
//   z==0: c = cell + relu(f)+relu(i)+relu(g) -> fp32 out_c
//   z==1: out_h = relu(o-gate)
// A = Wcat rows o (acc row), B = Tcat rows q (acc col).
// ---------------------------------------------------------------------------
__global__ __launch_bounds__(256)
void gemm_gateB(const unsigned short* __restrict__ Tcat,
                const unsigned short* __restrict__ Wcat,
                const float* __restrict__ cell,
                float* __restrict__ out_c, float* __restrict__ out_h)
{
    __shared__ alignas(16) unsigned short lds[16384];

    const int tid = threadIdx.x;
    const int lane = tid & 63;
    const int w = tid >> 6;
    const int zc = (blockIdx.z == 0);

    int orig = blockIdx.x + 4 * blockIdx.y;              // 0..511 per z-slice
    int swz = (orig & 7) * 64 + (orig >> 3);             // XCD chunk swizzle
    const int x = swz & 3;
    const int b = swz >> 2;
    const int to = (x >> 1) * 128;     // A rows: Wcat o
    const int tq = (x & 1) * 128;      // B rows: S_T q
    const int wm = (w >> 1) * 64;
    const int wn = (w & 1) * 64;

    const int nseg = zc ? 3 : 1;

    f32x4 accc[4][4];
#pragma unroll
    for (int m = 0; m < 4; ++m)
#pragma unroll
        for (int n = 0; n < 4; ++n)
            accc[m][n] = (f32x4){0.f, 0.f, 0.f, 0.f};

    for (int seg = 0; seg < nseg; ++seg) {
        int gv = zc ? (seg + (seg >> 1)) : 2;            // {0,1,3} or {2}
        const unsigned short* Ap = Wcat + (long)gv * 131072 + (long)to * 512;
        const unsigned short* Bp = Tcat + (long)gv * 16777216 + (long)b * 131072 + (long)tq * 512;
        f32x4 acc[4][4];
#pragma unroll
        for (int m = 0; m < 4; ++m)
#pragma unroll
            for (int n = 0; n < 4; ++n)
                acc[m][n] = (f32x4){0.f, 0.f, 0.f, 0.f};
        for (int ks = 0; ks < 8; ++ks) {
            if (seg + ks > 0) __syncthreads();
            stage_tile(Ap, 512, Bp, 512, lds, ks * 64, tid);
            __syncthreads();
            compute_tile(lds, lane, wm, wn, acc);        // acc[o_local][q_local]
        }
#pragma unroll
        for (int m = 0; m < 4; ++m)
#pragma unroll
            for (int n = 0; n < 4; ++n)
#pragma unroll
                for (int r = 0; r < 4; ++r) {
                    float v = acc[m][n][r];
                    accc[m][n][r] += (v > 0.f ? v : 0.f);
                }
    }

    const int r0 = (lane >> 4) * 4;
    const int c0 = lane & 15;
    if (zc) {
        const float* cb = cell + (long)b * 65536;
        float* co = out_c + (long)b * 65536;
#pragma unroll
        for (int m = 0; m < 4; ++m)
#pragma unroll
            for (int n = 0; n < 4; ++n)
#pragma unroll
                for (int r = 0; r < 4; ++r) {
                    int row = to + wm + m * 16 + r0 + r;   // o
                    int col = tq + wn + n * 16 + c0;       // q
                    co[(long)row * 256 + col] = accc[m][n][r] + cb[(long)row * 256 + col];
                }
    } else {
        float* ho = out_h + (long)b * 65536;
#pragma unroll
        for (int m = 0; m < 4; ++m)
#pragma unroll
            for (int n = 0; n < 4; ++n)
#pragma unroll
                for (int r = 0; r < 4; ++r) {
                    int row = to + wm + m * 16 + r0 + r;
                    int col = tq + wn + n * 16 + c0;
                    ho[(long)row * 256 + col] = accc[m][n][r];
                }
    }
}

// ---------------------------------------------------------------------------
// Final: out_h[b][o][q] += relu( sum_i Woc[o][i] * ScT[b][q][i] ), K=256.
// ---------------------------------------------------------------------------
__global__ __launch_bounds__(256)
void gemm_hfinal(const unsigned short* __restrict__ Wocb,
                 const unsigned short* __restrict__ ScT,
                 float* __restrict__ out_h)
{
    __shared__ alignas(16) unsigned short lds[16384];

    const int tid = threadIdx.x;
    const int lane = tid & 63;
    const int w = tid >> 6;

    int orig = blockIdx.x + 4 * blockIdx.y;
    int swz = (orig & 7) * 64 + (orig >> 3);
    const int x = swz & 3;
    const int b = swz >> 2;
    const int to = (x >> 1) * 128;
    const int tq = (x & 1) * 128;
    const int wm = (w >> 1) * 64;
    const int wn = (w & 1) * 64;

    const unsigned short* Ap = Wocb + (long)to * 256;
    const unsigned short* Bp = ScT + (long)b * 65536 + (long)tq * 256;

    f32x4 acc[4][4];
#pragma unroll
    for (int m = 0; m < 4; ++m)
#pragma unroll
        for (int n = 0; n < 4; ++n)
            acc[m][n] = (f32x4){0.f, 0.f, 0.f, 0.f};

    for (int t = 0; t < 4; ++t) {
        if (t > 0) __syncthreads();
        stage_tile(Ap, 256, Bp, 256, lds, t * 64, tid);
        __syncthreads();
        compute_tile(lds, lane, wm, wn, acc);
    }

    float* ho = out_h + (long)b * 65536;
    const int r0 = (lane >> 4) * 4;
    const int c0 = lane & 15;
#pragma unroll
    for (int m = 0; m < 4; ++m)
#pragma unroll
        for (int n = 0; n < 4; ++n)
#pragma unroll
            for (int r = 0; r < 4; ++r) {
                int row = to + wm + m * 16 + r0 + r;
                int col = tq + wn + n * 16 + c0;
                float v = acc[m][n][r];
                ho[(long)row * 256 + col] += (v > 0.f ? v : 0.f);
            }
}

// ---------------------------------------------------------------------------
extern "C" void kernel_launch(void* const* d_in, const int* in_sizes, int n_in,
                              void* d_out, int out_size, void* d_ws, size_t ws_size,
                              hipStream_t stream)
{
    (void)in_sizes; (void)n_in; (void)out_size; (void)ws_size;

    const float* X    = (const float*)d_in[0];
    const float* H    = (const float*)d_in[1];
    const float* cell = (const float*)d_in[2];
    const float* Wxp[4] = {(const float*)d_in[3], (const float*)d_in[4],
                           (const float*)d_in[5], (const float*)d_in[6]};
    const float* Whp[4] = {(const float*)d_in[7], (const float*)d_in[8],
                           (const float*)d_in[9], (const float*)d_in[10]};
    const float* Wocf = (const float*)d_in[11];

    float* out_h = (float*)d_out;                  // [128][256][256]
    float* out_c = out_h + 8388608;                // [128][256][256]

    unsigned short* ws   = (unsigned short*)d_ws;  // bf16 elements (ws = 256 MiB)
    unsigned short* ScT  = ws;                     //  8,388,608 el
    unsigned short* Wcat = ws + 16777216;          //    524,288 el [4][256][512]
    unsigned short* Wocb = ws + 17301504;          //     65,536 el
    unsigned short* Tcat = ws + 17367040;          // 67,108,864 el [4][128][256][512]

    // 1. weights -> bf16 (concatenated [Wx|Wh] per gate)
    cvt_weights<<<dim3(2304), 256, 0, stream>>>(Wxp[0], Wxp[1], Wxp[2], Wxp[3],
                                                Whp[0], Whp[1], Whp[2], Whp[3],
                                                Wocf, Wcat, Wocb);
    // 2. stage 1 all gates: S_T[g][b][q][i'] (reads X/H fp32 directly)
    gemm_stage1<0><<<dim3(4, 128, 8), 256, 0, stream>>>(X, H, Wcat, Tcat);
    // 3. stage 2 fused: z=0 -> c -> out_c ; z=1 -> ogate -> out_h
    gemm_gateB<<<dim3(4, 128, 2), 256, 0, stream>>>(Tcat, Wcat, cell, out_c, out_h);
    // 4. Sc_T[b][q][i] = (c . Woc^T)^T  (reads out_c fp32 directly)
    gemm_stage1<1><<<dim3(4, 128, 1), 256, 0, stream>>>(out_c, nullptr, Wocb, ScT);
    // 5. h = ogate + relu(Woc . Sc)  (fp32 RMW on out_h)
    gemm_hfinal<<<dim3(4, 128), 256, 0, stream>>>(Wocb, ScT, out_h);
}